// Round 2
// baseline (948.568 us; speedup 1.0000x reference)
//
#include <hip/hip_runtime.h>
#include <hip/hip_bf16.h>

// LGA3D2: out = A_g(A_g(x)); A_g is a 5x5 spatial x 3-depth guided aggregation.
// out[b,c,d,h,w] = sum_{i,j in 5x5, k in 0..2} g[b,(i*5+j)*3+k,h,w] * x[b,c,d+k-1,h+i-2,w+j-2]
// x: [B,C,D,H,W] fp32, g: [B,75,H,W] fp32.

constexpr int RAD = 2;
constexpr int BB = 2, CC = 16, DD = 48, HH = 128, WW = 256;
constexpr int GG = 75;
constexpr int PLANE = HH * WW;

constexpr int WPT = 4;            // outputs per thread along W
constexpr int NWT = WW / WPT;     // 64 w-threads (one wave spans W)
constexpr int DPG = 12;           // depths per thread
constexpr int NDG = DD / DPG;     // 4 depth groups -> 256 threads/block

__device__ __forceinline__ float bf2f(unsigned short u) {
  union { unsigned int i; float f; } c; c.i = ((unsigned int)u) << 16; return c.f;
}
__device__ __forceinline__ unsigned short f2bf(float f) {
  union { float f; unsigned int i; } c; c.f = f;
  unsigned int r = c.i + 0x7FFFu + ((c.i >> 16) & 1u);  // round-nearest-even
  return (unsigned short)(r >> 16);
}

__device__ __forceinline__ void load4(float* v, const float* p) {
  const float4 t = *reinterpret_cast<const float4*>(p);
  v[0] = t.x; v[1] = t.y; v[2] = t.z; v[3] = t.w;
}
__device__ __forceinline__ void load4(float* v, const __hip_bfloat16* p) {
  const ushort4 t = *reinterpret_cast<const ushort4*>(p);
  v[0] = bf2f(t.x); v[1] = bf2f(t.y); v[2] = bf2f(t.z); v[3] = bf2f(t.w);
}
__device__ __forceinline__ void store4(float* p, const float* v) {
  float4 t; t.x = v[0]; t.y = v[1]; t.z = v[2]; t.w = v[3];
  *reinterpret_cast<float4*>(p) = t;
}
__device__ __forceinline__ void store4(__hip_bfloat16* p, const float* v) {
  ushort4 t; t.x = f2bf(v[0]); t.y = f2bf(v[1]); t.z = f2bf(v[2]); t.w = f2bf(v[3]);
  *reinterpret_cast<ushort4*>(p) = t;
}

// One pass. Block = (b, c, h); 256 threads = 64 w-threads x 4 depth-groups.
// Each thread: WPT=4 w-outputs x DPG=12 depth-outputs, accumulated in registers.
// Scatter over depth: x row at depth d contributes k=0,1,2 to out depths d+1,d,d-1.
template <typename IT, typename OT>
__global__ __launch_bounds__(256) void lga_pass(const IT* __restrict__ x,
                                                const float* __restrict__ g,
                                                OT* __restrict__ out) {
  // XCD-bijective swizzle: nwg=4096 (div by 8). Consecutive logical ids
  // (varying h fastest) stay on ONE XCD -> 5-row h-halo hits that XCD's L2.
  constexpr int NWG = BB * CC * HH;       // 4096
  const int bx = blockIdx.x;
  const int lid = (bx & 7) * (NWG >> 3) + (bx >> 3);
  const int h = lid % HH;
  const int c = (lid / HH) % CC;
  const int b = lid / (HH * CC);

  const int wt = threadIdx.x & 63;        // w-thread within wave
  const int dg = threadIdx.x >> 6;        // depth group (wave-uniform)
  const int w0 = wt * WPT;
  const int d0 = dg * DPG;
  const bool wok_lo = (wt > 0);
  const bool wok_hi = (wt < NWT - 1);

  float acc[DPG][WPT];
#pragma unroll
  for (int a = 0; a < DPG; ++a)
#pragma unroll
    for (int q = 0; q < WPT; ++q) acc[a][q] = 0.f;

  const IT* xb = x + (size_t)(b * CC + c) * DD * PLANE;
  const float* gp = g + (size_t)b * GG * PLANE + (size_t)h * WW + w0;

  for (int i = 0; i < 5; ++i) {
    const int hr = h + i - RAD;
    if (hr < 0 || hr >= HH) continue;     // block-uniform (zero pad)

    // Guidance for this i-row: channels i*15 .. i*15+14, float4 at (h, w0).
    // Cached in registers, reused across all 14 depth rows below.
    float gr[15][4];
#pragma unroll
    for (int t = 0; t < 15; ++t) load4(gr[t], gp + (size_t)(i * 15 + t) * PLANE);

    const IT* xrow = xb + (size_t)hr * WW;

#pragma unroll
    for (int a = -1; a <= DPG; ++a) {     // x depth rows d0-1 .. d0+DPG
      bool dok = true;
      if (a == -1)  dok = (d0 > 0);               // depth zero-pad low
      if (a == DPG) dok = (d0 + DPG < DD);        // depth zero-pad high

      // 12-value register window covering w = w0-4 .. w0+7 (3 aligned float4)
      float v[12];
      if (dok) {
        const IT* rp = xrow + (size_t)(d0 + a) * PLANE + w0;
        if (wok_lo) load4(v + 0, rp - 4);
        else { v[0] = v[1] = v[2] = v[3] = 0.f; }
        load4(v + 4, rp);
        if (wok_hi) load4(v + 8, rp + 4);
        else { v[8] = v[9] = v[10] = v[11] = 0.f; }
      } else {
#pragma unroll
        for (int t = 0; t < 12; ++t) v[t] = 0.f;
      }

#pragma unroll
      for (int j = 0; j < 5; ++j)
#pragma unroll
        for (int k = 0; k < 3; ++k) {
          const int ai = a + 1 - k;       // output depth index (compile-time)
          if (ai < 0 || ai >= DPG) continue;
#pragma unroll
          for (int q = 0; q < WPT; ++q)
            acc[ai][q] = fmaf(gr[j * 3 + k][q], v[q + j + 2], acc[ai][q]);
        }
    }
  }

  OT* ob = out + ((size_t)(b * CC + c) * DD + d0) * PLANE + (size_t)h * WW + w0;
#pragma unroll
  for (int ai = 0; ai < DPG; ++ai) store4(ob + (size_t)ai * PLANE, acc[ai]);
}

extern "C" void kernel_launch(void* const* d_in, const int* in_sizes, int n_in,
                              void* d_out, int out_size, void* d_ws, size_t ws_size,
                              hipStream_t stream) {
  const float* x = (const float*)d_in[0];
  const float* g = (const float*)d_in[1];
  float* out = (float*)d_out;

  const size_t elems = (size_t)BB * CC * DD * HH * WW;
  const dim3 grid(BB * CC * HH);
  const dim3 block(NWT * NDG);   // 256

  if (ws_size >= elems * sizeof(float)) {
    float* y = (float*)d_ws;
    lga_pass<float, float><<<grid, block, 0, stream>>>(x, g, y);
    lga_pass<float, float><<<grid, block, 0, stream>>>(y, g, out);
  } else {
    __hip_bfloat16* y = (__hip_bfloat16*)d_ws;
    lga_pass<float, __hip_bfloat16><<<grid, block, 0, stream>>>(x, g, y);
    lga_pass<__hip_bfloat16, float><<<grid, block, 0, stream>>>(y, g, out);
  }
}